// Round 4
// baseline (441.244 us; speedup 1.0000x reference)
//
#include <hip/hip_runtime.h>

typedef short short8 __attribute__((ext_vector_type(8)));
typedef float f32x4 __attribute__((ext_vector_type(4)));

#define EPS 0.012f

__device__ __forceinline__ unsigned short rne_bf16(float v) {
    unsigned u = __float_as_uint(v);
    unsigned r = u + 0x7FFFu + ((u >> 16) & 1u);
    return (unsigned short)(r >> 16);
}
__device__ __forceinline__ float bf16_to_f(unsigned short h) {
    return __uint_as_float(((unsigned)h) << 16);
}

__global__ __launch_bounds__(256, 3) void vq_kernel(
    const float* __restrict__ x, const float* __restrict__ emb,
    float* __restrict__ out_q, float* __restrict__ out_enc,
    float* __restrict__ out_dist, float* __restrict__ out_loss)
{
    // bf16 hi/lo tiles, XOR-swizzled: short_idx = row*64 + (d0 ^ ((row&7)<<3))
    __shared__ __align__(16) unsigned short xhi[64 * 64];
    __shared__ __align__(16) unsigned short xlo[64 * 64];
    __shared__ __align__(16) unsigned short ehi[128 * 64];
    __shared__ __align__(16) unsigned short elo[128 * 64];
    __shared__ float xpart[256];
    __shared__ float xx_s[64];
    __shared__ float ee_s[128];
    __shared__ int   enc_s[64];
    __shared__ float red_s[4];

    const int t   = threadIdx.x;
    const int bid = blockIdx.x;              // 2048 blocks x 64 rows (b,h fixed; rows = w)
    const int n_base = bid * 64;
    const size_t xbase = (size_t)(bid >> 6) * 262144 + (size_t)(bid & 63) * 64;
    const int l  = t & 63;                   // lane in wave
    const int wv = t >> 6;                   // wave 0..3 (owns rows wv*16..wv*16+15)

    // ---- stage x: fp32 -> bf16 hi/lo (split precision), fp32 norms ----
    {
        const int w  = t & 63;
        const int dg = t >> 6;               // 16 d's per thread
        float part = 0.f;
        #pragma unroll
        for (int g = 0; g < 2; ++g) {
            int d0 = dg * 16 + g * 8;
            short8 h8, l8;
            #pragma unroll
            for (int i = 0; i < 8; ++i) {
                float v = x[xbase + (size_t)(d0 + i) * 4096 + w];
                part = fmaf(v, v, part);
                unsigned short hb = rne_bf16(v);
                float hv = bf16_to_f(hb);
                unsigned short lb = rne_bf16(v - hv);   // exact residual, re-rounded
                h8[i] = (short)hb; l8[i] = (short)lb;
            }
            int idx = w * 64 + (d0 ^ ((w & 7) << 3));
            *(short8*)&xhi[idx] = h8;
            *(short8*)&xlo[idx] = l8;
        }
        xpart[dg * 64 + w] = part;
    }
    __syncthreads();
    if (t < 64) xx_s[t] = (xpart[t] + xpart[64 + t]) + (xpart[128 + t] + xpart[192 + t]);
    __syncthreads();

    // ---- per-lane A fragments (constant across all k) ----
    // A layout (16x32): row = lane&15, k = (lane>>4)*8 + i
    const int arow = wv * 16 + (l & 15);
    const int asw  = (arow & 7) << 3;
    const int ad0  = (l >> 4) * 8;
    short8 ahi0 = *(short8*)&xhi[arow * 64 + (ad0 ^ asw)];
    short8 ahi1 = *(short8*)&xhi[arow * 64 + ((ad0 + 32) ^ asw)];
    short8 alo0 = *(short8*)&xlo[arow * 64 + (ad0 ^ asw)];
    short8 alo1 = *(short8*)&xlo[arow * 64 + ((ad0 + 32) ^ asw)];
    // C/D layout: col = lane&15 (k), row = (lane>>4)*4 + reg
    const int rlw0 = (l >> 4) * 4;
    const int n0   = n_base + wv * 16 + rlw0;
    float xx4[4];
    #pragma unroll
    for (int r = 0; r < 4; ++r) xx4[r] = xx_s[wv * 16 + rlw0 + r];

    float m1[4], m2[4]; int k1[4];
    #pragma unroll
    for (int r = 0; r < 4; ++r) { m1[r] = 3.4e38f; m2[r] = 3.4e38f; k1[r] = 0; }

    float* dbase = out_dist + (size_t)n0 * 512 + (l & 15);

    for (int kc = 0; kc < 4; ++kc) {
        __syncthreads();   // previous chunk's readers done before overwrite
        // ---- stage emb chunk -> bf16 hi/lo (coalesced 32B/lane global reads) ----
        #pragma unroll
        for (int it = 0; it < 4; ++it) {
            int flat = t + it * 256;         // 0..1023 units of 8 d
            int kr = flat >> 3;              // 0..127
            int d0 = (flat & 7) * 8;
            const float* src = emb + (size_t)(kc * 128 + kr) * 64 + d0;
            float4 v0 = *(const float4*)src;
            float4 v1 = *(const float4*)(src + 4);
            float vv[8] = {v0.x, v0.y, v0.z, v0.w, v1.x, v1.y, v1.z, v1.w};
            short8 h8, l8;
            #pragma unroll
            for (int i = 0; i < 8; ++i) {
                unsigned short hb = rne_bf16(vv[i]);
                float hv = bf16_to_f(hb);
                unsigned short lb = rne_bf16(vv[i] - hv);
                h8[i] = (short)hb; l8[i] = (short)lb;
            }
            int idx = kr * 64 + (d0 ^ ((kr & 7) << 3));
            *(short8*)&ehi[idx] = h8;
            *(short8*)&elo[idx] = l8;
        }
        __syncthreads();
        if (t < 128) {                        // ||e_k||^2 from hi+lo (err ~2^-17 rel)
            float s = 0.f;
            #pragma unroll
            for (int dg8 = 0; dg8 < 8; ++dg8) {
                int idx = t * 64 + ((dg8 * 8) ^ ((t & 7) << 3));
                short8 h  = *(short8*)&ehi[idx];
                short8 lo = *(short8*)&elo[idx];
                #pragma unroll
                for (int i = 0; i < 8; ++i) {
                    float e = bf16_to_f((unsigned short)h[i]) + bf16_to_f((unsigned short)lo[i]);
                    s = fmaf(e, e, s);
                }
            }
            ee_s[t] = s;
        }
        __syncthreads();

        // ---- 8 k-tiles: 6 MFMAs each (hh + lh + hl), finalize + store + min ----
        #pragma unroll 1
        for (int kt = 0; kt < 8; ++kt) {
            int kl   = kt * 16 + (l & 15);    // B col = lane&15 -> codebook row kl
            int bix  = kl * 64;
            int bsw  = (kl & 7) << 3;
            int bd0  = (l >> 4) * 8;
            short8 bh0 = *(short8*)&ehi[bix + (bd0 ^ bsw)];
            short8 bh1 = *(short8*)&ehi[bix + ((bd0 + 32) ^ bsw)];
            short8 bl0 = *(short8*)&elo[bix + (bd0 ^ bsw)];
            short8 bl1 = *(short8*)&elo[bix + ((bd0 + 32) ^ bsw)];
            f32x4 acc = {0.f, 0.f, 0.f, 0.f};
            acc = __builtin_amdgcn_mfma_f32_16x16x32_bf16(ahi0, bh0, acc, 0, 0, 0);
            acc = __builtin_amdgcn_mfma_f32_16x16x32_bf16(ahi1, bh1, acc, 0, 0, 0);
            acc = __builtin_amdgcn_mfma_f32_16x16x32_bf16(alo0, bh0, acc, 0, 0, 0);
            acc = __builtin_amdgcn_mfma_f32_16x16x32_bf16(alo1, bh1, acc, 0, 0, 0);
            acc = __builtin_amdgcn_mfma_f32_16x16x32_bf16(ahi0, bl0, acc, 0, 0, 0);
            acc = __builtin_amdgcn_mfma_f32_16x16x32_bf16(ahi1, bl1, acc, 0, 0, 0);
            float eek = ee_s[kl];
            int kg = kc * 128 + kl;           // ascending over (kc,kt) => first-min tie-break
            float* dp = dbase + kc * 128 + kt * 16;
            #pragma unroll
            for (int r = 0; r < 4; ++r) {
                float dist = fmaf(acc[r], -2.f, xx4[r] + eek);
                dp[(size_t)r * 512] = dist;
                if (dist < m1[r]) { m2[r] = m1[r]; m1[r] = dist; k1[r] = kg; }
                else if (dist < m2[r]) m2[r] = dist;
            }
        }
    }

    __syncthreads();   // drains vmcnt: dist stores complete (needed for rare readback)

    // ---- per-row argmin across 16 k-lanes + rare fp64 refinement; loss = dist[enc] ----
    float lacc = 0.f;
    {
        const unsigned long long gmask = 0xFFFFull << ((l >> 4) << 4);
        #pragma unroll 1
        for (int r = 0; r < 4; ++r) {
            float bv = m1[r]; int bk = k1[r];
            #pragma unroll
            for (int m = 1; m < 16; m <<= 1) {
                float ov = __shfl_xor(bv, m, 64);
                int   ok = __shfl_xor(bk, m, 64);
                if (ov < bv || (ov == bv && ok < bk)) { bv = ov; bk = ok; }
            }
            float thr = bv + EPS;
            unsigned long long b1 = __ballot(m1[r] <= thr);
            unsigned long long b2 = __ballot(m2[r] <= thr);
            int enc = bk; float lossv = bv;
            if (__popcll(b1 & gmask) > 1 || (b2 & gmask) != 0ULL) {
                bool active = (m1[r] <= thr) || (m2[r] <= thr);
                double bestv = 1e300; int bestk = 0x7fffffff;
                const int w = wv * 16 + rlw0 + r;     // row == w coordinate
                if (active) {
                    #pragma unroll 1
                    for (int kk = 0; kk < 32; ++kk) {
                        int k = kk * 16 + (l & 15);
                        double s = 0.0;
                        #pragma unroll 1
                        for (int d = 0; d < 64; ++d) {
                            double df = (double)x[xbase + (size_t)d * 4096 + w]
                                      - (double)emb[k * 64 + d];
                            s += df * df;
                        }
                        if (s < bestv) { bestv = s; bestk = k; }   // ascending k, strict <
                    }
                }
                #pragma unroll
                for (int m = 1; m < 16; m <<= 1) {
                    double ov = __shfl_xor(bestv, m, 64);
                    int   ok  = __shfl_xor(bestk, m, 64);
                    if (ov < bestv || (ov == bestv && ok < bestk)) { bestv = ov; bestk = ok; }
                }
                enc = bestk;
                if ((l & 15) == 0 && enc != bk)
                    lossv = out_dist[(size_t)(n0 + r) * 512 + enc];
            }
            if ((l & 15) == 0) {
                enc_s[wv * 16 + rlw0 + r] = enc;
                out_enc[n0 + r] = (float)enc;
                lacc += lossv;     // sum (q-x)^2 over row == dist[row][enc]
            }
        }
    }
    #pragma unroll
    for (int m = 32; m >= 1; m >>= 1) lacc += __shfl_down(lacc, m, 64);
    if (l == 0) red_s[wv] = lacc;
    __syncthreads();
    if (t == 0)
        atomicAdd(out_loss, (red_s[0] + red_s[1] + red_s[2] + red_s[3]) * (1.0f / 8388608.0f));

    // ---- quantized gather (codebook L2-resident) + coalesced store ----
    {
        const int w  = t & 63;
        const int dg = t >> 6;
        const int e  = enc_s[w];
        const float* er = emb + e * 64 + dg * 16;
        float* qp = out_q + xbase + (size_t)(dg * 16) * 4096 + w;
        #pragma unroll
        for (int qi = 0; qi < 4; ++qi) {
            float4 q4 = *(const float4*)(er + qi * 4);
            qp[(size_t)(qi * 4 + 0) * 4096] = q4.x;
            qp[(size_t)(qi * 4 + 1) * 4096] = q4.y;
            qp[(size_t)(qi * 4 + 2) * 4096] = q4.z;
            qp[(size_t)(qi * 4 + 3) * 4096] = q4.w;
        }
    }
}

extern "C" void kernel_launch(void* const* d_in, const int* in_sizes, int n_in,
                              void* d_out, int out_size, void* d_ws, size_t ws_size,
                              hipStream_t stream) {
    const float* x   = (const float*)d_in[0];   // [32,64,64,64]
    const float* emb = (const float*)d_in[1];   // [512,64]

    float* out_q    = (float*)d_out;            // 8388608
    float* out_enc  = out_q + 8388608;          // 131072
    float* out_dist = out_enc + 131072;         // 67108864
    float* out_loss = out_dist + 67108864;      // 1

    hipMemsetAsync(out_loss, 0, sizeof(float), stream);
    vq_kernel<<<2048, 256, 0, stream>>>(x, emb, out_q, out_enc, out_dist, out_loss);
}

// Round 5
// 111.594 us; speedup vs baseline: 3.9540x; 3.9540x over previous
//
#include <hip/hip_runtime.h>

typedef short short8 __attribute__((ext_vector_type(8)));
typedef float f32x4 __attribute__((ext_vector_type(4)));

#define EPS 0.012f   // > 4x worst-case bf16-split dist error (~1.5e-3 + norm err)

__device__ __forceinline__ unsigned short rne_bf16(float v) {
    unsigned u = __float_as_uint(v);
    unsigned r = u + 0x7FFFu + ((u >> 16) & 1u);
    return (unsigned short)(r >> 16);
}
__device__ __forceinline__ float bf16_to_f(unsigned short h) {
    return __uint_as_float(((unsigned)h) << 16);
}
// xs swizzle at float4 granularity: float index = row*64 + (d ^ ((row&15)<<2))
__device__ __forceinline__ int xsw(int row, int d4) {
    return row * 64 + (d4 ^ ((row & 15) << 2));
}

#define MFMA(a,b,c) __builtin_amdgcn_mfma_f32_16x16x32_bf16((a),(b),(c),0,0,0)

__global__ __launch_bounds__(512, 4) void vq_kernel(
    const float* __restrict__ x, const float* __restrict__ emb,
    float* __restrict__ out_q, float* __restrict__ out_enc,
    float* __restrict__ out_dist, float* __restrict__ out_loss)
{
    __shared__ __align__(16) float xs[128 * 64];             // fp32 x tile, float4-swizzled
    __shared__ __align__(16) unsigned short ehi[128 * 64];   // bf16 hi, short8-swizzled
    __shared__ __align__(16) unsigned short elo[128 * 64];   // bf16 lo residual
    __shared__ float xpart[4][128];
    __shared__ float xx_s[128];
    __shared__ float ee_s[128];
    __shared__ int   enc_s[128];
    __shared__ float red_s[8];

    const int t   = threadIdx.x;
    const int bid = blockIdx.x;              // 1024 blocks x 128 rows (row = hh*64 + w)
    const int n_base = bid * 128;
    const int b   = bid >> 5;
    const int h0  = (bid & 31) * 2;
    const size_t xb0 = (size_t)b * 262144 + (size_t)h0 * 64;  // + d*4096 + hh*64 + w
    const int l  = t & 63;
    const int wv = t >> 6;                   // 8 waves; wave owns rows wv*16..+15

    // ---- stage x tile fp32 (coalesced scalar loads, float4 LDS writes) ----
    {
        const int w  = t & 63;
        const int q  = t >> 6;               // 0..7
        const int hh = q & 1;
        const int c0 = q >> 1;               // quads c0, c0+4, c0+8, c0+12
        const int row = hh * 64 + w;
        const size_t gb = xb0 + hh * 64 + w;
        float part = 0.f;
        #pragma unroll
        for (int cc = 0; cc < 4; ++cc) {
            int d4 = (c0 + cc * 4) * 4;
            float4 v;
            v.x = x[gb + (size_t)(d4 + 0) * 4096];
            v.y = x[gb + (size_t)(d4 + 1) * 4096];
            v.z = x[gb + (size_t)(d4 + 2) * 4096];
            v.w = x[gb + (size_t)(d4 + 3) * 4096];
            part = fmaf(v.x, v.x, part); part = fmaf(v.y, v.y, part);
            part = fmaf(v.z, v.z, part); part = fmaf(v.w, v.w, part);
            *(float4*)&xs[xsw(row, d4)] = v;
        }
        xpart[c0][row] = part;
    }
    __syncthreads();
    if (t < 128) xx_s[t] = (xpart[0][t] + xpart[1][t]) + (xpart[2][t] + xpart[3][t]);

    // ---- A fragments: read own x row from LDS, bf16 hi/lo split in registers ----
    // A layout (16x32): row = lane&15, k = (lane>>4)*8 + i   (validated R4)
    const int arow = wv * 16 + (l & 15);
    const int ad0  = (l >> 4) * 8;
    short8 ahi0, ahi1, alo0, alo1;
    {
        float va[16];
        *(float4*)&va[0]  = *(const float4*)&xs[xsw(arow, ad0)];
        *(float4*)&va[4]  = *(const float4*)&xs[xsw(arow, ad0 + 4)];
        *(float4*)&va[8]  = *(const float4*)&xs[xsw(arow, ad0 + 32)];
        *(float4*)&va[12] = *(const float4*)&xs[xsw(arow, ad0 + 36)];
        #pragma unroll
        for (int i = 0; i < 8; ++i) {
            unsigned short hb = rne_bf16(va[i]);
            ahi0[i] = (short)hb; alo0[i] = (short)rne_bf16(va[i] - bf16_to_f(hb));
            unsigned short hb2 = rne_bf16(va[8 + i]);
            ahi1[i] = (short)hb2; alo1[i] = (short)rne_bf16(va[8 + i] - bf16_to_f(hb2));
        }
    }
    __syncthreads();   // xx_s ready for all

    // C/D layout: col = lane&15 (k), row = (lane>>4)*4 + reg   (validated R4)
    const int rlw0 = (l >> 4) * 4;
    const int n0   = n_base + wv * 16 + rlw0;
    float xx4[4];
    #pragma unroll
    for (int r = 0; r < 4; ++r) xx4[r] = xx_s[wv * 16 + rlw0 + r];

    float m1[4], m2[4]; int k1[4];
    #pragma unroll
    for (int r = 0; r < 4; ++r) { m1[r] = 3.4e38f; m2[r] = 3.4e38f; k1[r] = 0; }

    float* dbase = out_dist + (size_t)n0 * 512 + (l & 15);

    for (int kc = 0; kc < 4; ++kc) {
        __syncthreads();   // protect ehi/elo from previous chunk readers
        // ---- stage emb chunk -> bf16 hi/lo; fused ||e||^2 via 8-lane shfl ----
        float s01[2];
        #pragma unroll
        for (int it = 0; it < 2; ++it) {
            int flat = t + it * 512;         // 1024 units of 8 floats
            int kr = flat >> 3;
            int d0 = (flat & 7) * 8;
            const float* src = emb + (size_t)(kc * 128 + kr) * 64 + d0;
            float4 v0 = *(const float4*)src;
            float4 v1 = *(const float4*)(src + 4);
            float vv[8] = {v0.x, v0.y, v0.z, v0.w, v1.x, v1.y, v1.z, v1.w};
            short8 h8, l8; float s = 0.f;
            #pragma unroll
            for (int i = 0; i < 8; ++i) {
                s = fmaf(vv[i], vv[i], s);
                unsigned short hb = rne_bf16(vv[i]);
                h8[i] = (short)hb; l8[i] = (short)rne_bf16(vv[i] - bf16_to_f(hb));
            }
            int idx = kr * 64 + (d0 ^ ((kr & 7) << 3));
            *(short8*)&ehi[idx] = h8;
            *(short8*)&elo[idx] = l8;
            s01[it] = s;
        }
        #pragma unroll
        for (int m = 1; m < 8; m <<= 1) {
            s01[0] += __shfl_xor(s01[0], m, 64);
            s01[1] += __shfl_xor(s01[1], m, 64);
        }
        if ((t & 7) == 0) {
            ee_s[t >> 3]        = s01[0];
            ee_s[64 + (t >> 3)] = s01[1];
        }
        __syncthreads();

        // ---- 8 k-tiles: 6 MFMAs (two 3-chains), finalize + store + min-track ----
        #pragma unroll 1
        for (int kt = 0; kt < 8; ++kt) {
            int kl  = kt * 16 + (l & 15);    // B col = lane&15 -> codebook row kl
            int bix = kl * 64;
            int bsw = (kl & 7) << 3;
            int bd0 = (l >> 4) * 8;
            short8 bh0 = *(short8*)&ehi[bix + (bd0 ^ bsw)];
            short8 bh1 = *(short8*)&ehi[bix + ((bd0 + 32) ^ bsw)];
            short8 bl0 = *(short8*)&elo[bix + (bd0 ^ bsw)];
            short8 bl1 = *(short8*)&elo[bix + ((bd0 + 32) ^ bsw)];
            f32x4 accA = {0.f, 0.f, 0.f, 0.f};
            f32x4 accB = {0.f, 0.f, 0.f, 0.f};
            accA = MFMA(ahi0, bh0, accA);
            accB = MFMA(ahi1, bh1, accB);
            accA = MFMA(alo0, bh0, accA);
            accB = MFMA(alo1, bh1, accB);
            accA = MFMA(ahi0, bl0, accA);
            accB = MFMA(ahi1, bl1, accB);
            float eek = ee_s[kl];
            int kg = kc * 128 + kl;          // ascending over (kc,kt) => first-min tie-break
            float* dp = dbase + kc * 128 + kt * 16;
            #pragma unroll
            for (int r = 0; r < 4; ++r) {
                float dist = fmaf(accA[r] + accB[r], -2.f, xx4[r] + eek);
                dp[(size_t)r * 512] = dist;
                if (dist < m1[r]) { m2[r] = m1[r]; m1[r] = dist; k1[r] = kg; }
                else if (dist < m2[r]) m2[r] = dist;
            }
        }
    }

    __syncthreads();   // drains vmcnt: all dist stores complete (refine readback)

    // ---- per-row argmin + rare candidate-only fp64 refinement ----
    float lacc = 0.f;
    {
        const unsigned long long gmask = 0xFFFFull << ((l >> 4) << 4);
        #pragma unroll 1
        for (int r = 0; r < 4; ++r) {
            float bv = m1[r]; int bk = k1[r];
            #pragma unroll
            for (int m = 1; m < 16; m <<= 1) {
                float ov = __shfl_xor(bv, m, 64);
                int   ok = __shfl_xor(bk, m, 64);
                if (ov < bv || (ov == bv && ok < bk)) { bv = ov; bk = ok; }
            }
            float thr = bv + EPS;
            unsigned long long b1 = __ballot(m1[r] <= thr);
            unsigned long long b2 = __ballot(m2[r] <= thr);
            int enc = bk; float lossv = bv;
            if (__popcll(b1 & gmask) > 1 || (b2 & gmask) != 0ULL) {
                // rare: readback own row (L2-hot), fp64 only for actual candidates
                const int rowg = wv * 16 + rlw0 + r;
                const float* drow = out_dist + (size_t)(n_base + rowg) * 512 + (l & 15) * 32;
                double bestv = 1e300; int bestk = 0x7fffffff;
                #pragma unroll 1
                for (int c4 = 0; c4 < 8; ++c4) {
                    float4 dv = *(const float4*)(drow + c4 * 4);
                    float dvv[4] = {dv.x, dv.y, dv.z, dv.w};
                    #pragma unroll 1
                    for (int j = 0; j < 4; ++j) {
                        if (dvv[j] <= thr) {
                            int k = (l & 15) * 32 + c4 * 4 + j;
                            const float* er = emb + k * 64;
                            double s = 0.0;
                            #pragma unroll 4
                            for (int d = 0; d < 64; d += 4) {
                                float4 ev = *(const float4*)(er + d);
                                float4 xv = *(const float4*)&xs[xsw(rowg, d)];
                                double d0_ = (double)xv.x - (double)ev.x;
                                double d1_ = (double)xv.y - (double)ev.y;
                                double d2_ = (double)xv.z - (double)ev.z;
                                double d3_ = (double)xv.w - (double)ev.w;
                                s += d0_ * d0_ + d1_ * d1_ + d2_ * d2_ + d3_ * d3_;
                            }
                            if (s < bestv) { bestv = s; bestk = k; }  // ascending k, strict <
                        }
                    }
                }
                #pragma unroll
                for (int m = 1; m < 16; m <<= 1) {
                    double ov = __shfl_xor(bestv, m, 64);
                    int   ok  = __shfl_xor(bestk, m, 64);
                    if (ov < bestv || (ov == bestv && ok < bestk)) { bestv = ov; bestk = ok; }
                }
                enc = bestk;
                if ((l & 15) == 0 && enc != bk)
                    lossv = out_dist[(size_t)(n_base + rowg) * 512 + enc];
            }
            if ((l & 15) == 0) {
                enc_s[wv * 16 + rlw0 + r] = enc;
                out_enc[n0 + r] = (float)enc;
                lacc += lossv;   // sum over row of (q-x)^2 == dist[row][enc]
            }
        }
    }
    #pragma unroll
    for (int m = 32; m >= 1; m >>= 1) lacc += __shfl_down(lacc, m, 64);
    if (l == 0) red_s[wv] = lacc;
    __syncthreads();
    if (t == 0) {
        float tot = 0.f;
        #pragma unroll
        for (int i = 0; i < 8; ++i) tot += red_s[i];
        atomicAdd(out_loss, tot * (1.0f / 8388608.0f));
    }

    // ---- quantized gather (codebook L2-resident) + coalesced store ----
    {
        const int w   = t & 63;
        const int q   = t >> 6;
        const int hh  = q & 1;
        const int dg  = q >> 1;              // 0..3 -> d = dg*16..+15
        const int row = hh * 64 + w;
        const int e   = enc_s[row];
        const float* er = emb + e * 64 + dg * 16;
        float* qp = out_q + xb0 + (size_t)(dg * 16) * 4096 + hh * 64 + w;
        #pragma unroll
        for (int qi = 0; qi < 4; ++qi) {
            float4 q4 = *(const float4*)(er + qi * 4);
            qp[(size_t)(qi * 4 + 0) * 4096] = q4.x;
            qp[(size_t)(qi * 4 + 1) * 4096] = q4.y;
            qp[(size_t)(qi * 4 + 2) * 4096] = q4.z;
            qp[(size_t)(qi * 4 + 3) * 4096] = q4.w;
        }
    }
}

extern "C" void kernel_launch(void* const* d_in, const int* in_sizes, int n_in,
                              void* d_out, int out_size, void* d_ws, size_t ws_size,
                              hipStream_t stream) {
    const float* x   = (const float*)d_in[0];   // [32,64,64,64]
    const float* emb = (const float*)d_in[1];   // [512,64]

    float* out_q    = (float*)d_out;            // 8388608
    float* out_enc  = out_q + 8388608;          // 131072
    float* out_dist = out_enc + 131072;         // 67108864
    float* out_loss = out_dist + 67108864;      // 1

    hipMemsetAsync(out_loss, 0, sizeof(float), stream);
    vq_kernel<<<1024, 512, 0, stream>>>(x, emb, out_q, out_enc, out_dist, out_loss);
}